// Round 2
// baseline (3451.839 us; speedup 1.0000x reference)
//
#include <hip/hip_runtime.h>
#include <hip/hip_bf16.h>
#include <stdint.h>

// Problem constants (from reference)
#define B_    4
#define T_    1024
#define H_    2048          // K, also bytes/row in fp8
#define V_    32000
#define M_TOK (B_ * T_)     // 4096 tokens
#define BM    128
#define BN    128
#define BKB   128           // K-tile in fp8 bytes
#define NVT   (V_ / BN)     // 250 vocab tiles
#define KITER (H_ / BKB)    // 16 K-steps
#define BETA_   0.1f
#define EPS_LO_ 0.2f
#define EPS_HI_ 0.2f
#define WSCALE  16.0f       // W pre-scale (keeps e4m3 in normal range)
#define WINV    0.0625f     // epilogue compensation

typedef int   v8i  __attribute__((ext_vector_type(8)));
typedef int   v4i  __attribute__((ext_vector_type(4)));
typedef float f32x4 __attribute__((ext_vector_type(4)));

__device__ __forceinline__ void load16_lds(const void* g, void* l) {
    __builtin_amdgcn_global_load_lds(
        (const __attribute__((address_space(1))) unsigned int*)g,
        (__attribute__((address_space(3))) unsigned int*)l, 16, 0, 0);
}

// fp32 -> fp8 e4m3 (OCP on gfx950), 8 elements/thread: read 32B, write 8B
__global__ __launch_bounds__(256) void cvt_fp8(const float4* __restrict__ in,
                                               uint2* __restrict__ out, int n8,
                                               float scale) {
    int i = blockIdx.x * blockDim.x + threadIdx.x;
    if (i >= n8) return;
    float4 a = in[2 * i];
    float4 b = in[2 * i + 1];
    int lo = 0, hi = 0;
    lo = __builtin_amdgcn_cvt_pk_fp8_f32(a.x * scale, a.y * scale, lo, false);
    lo = __builtin_amdgcn_cvt_pk_fp8_f32(a.z * scale, a.w * scale, lo, true);
    hi = __builtin_amdgcn_cvt_pk_fp8_f32(b.x * scale, b.y * scale, hi, false);
    hi = __builtin_amdgcn_cvt_pk_fp8_f32(b.z * scale, b.w * scale, hi, true);
    uint2 r;
    r.x = (unsigned)lo;
    r.y = (unsigned)hi;
    out[i] = r;
}

// Fused MX-fp8 GEMM + exp-sum tile reduction + selected-logit pick.
// grid = (M_TOK/BM, V_/BN, 2)  z=0: policy, z=1: reference
__global__ __launch_bounds__(256, 2) void gemm_lse(
    const uint8_t* __restrict__ Xp, const uint8_t* __restrict__ Wp,
    const uint8_t* __restrict__ Xr, const uint8_t* __restrict__ Wr,
    const int* __restrict__ ids,
    float* __restrict__ part_p, float* __restrict__ part_r,
    float* __restrict__ sel_p,  float* __restrict__ sel_r)
{
    const int tid  = threadIdx.x;
    const int lane = tid & 63;
    const int wid  = tid >> 6;
    const int wm   = wid >> 1;   // wave row (0..1), 64 tokens
    const int wn   = wid & 1;    // wave col (0..1), 64 vocab
    const int tm   = blockIdx.x;
    const int tn   = blockIdx.y;
    const int z    = blockIdx.z;

    const uint8_t* X = z ? Xr : Xp;
    const uint8_t* W = z ? Wr : Wp;
    float* part = z ? part_r : part_p;
    float* sel  = z ? sel_r  : sel_p;

    const int rowA = tm * BM;
    const int colB = tn * BN;

    __shared__ __align__(16) uint8_t As[BM * BKB];   // [128][128B], 16KB
    __shared__ __align__(16) uint8_t Bs[BN * BKB];
    __shared__ float sums_s[2][BM];
    __shared__ int   ids_s[BM];

    if (tid < BM) ids_s[tid] = ids[rowA + tid];

    // Staging: one global_load_lds = 64 lanes x 16B = 8 rows x 128B.
    // LDS dest is wave-uniform base + lane*16 (lane l -> row l>>3, phys chunk l&7).
    // XOR-swizzle on the GLOBAL side: phys chunk p holds logical chunk p ^ (row&7),
    // so frag reads (row stride 128B = 32 banks) spread across all bank groups.
    const int l8 = lane >> 3;                 // row within 8-row group
    const int lc = ((lane & 7) ^ l8) << 4;    // logical byte offset in 128B window
    const uint8_t* gA[4]; const uint8_t* gB[4];
    uint8_t* lA[4]; uint8_t* lB[4];
    #pragma unroll
    for (int j = 0; j < 4; ++j) {
        const int g = wid * 4 + j;            // 8-row group 0..15
        gA[j] = X + (size_t)(rowA + g * 8 + l8) * H_ + lc;
        gB[j] = W + (size_t)(colB + g * 8 + l8) * H_ + lc;
        lA[j] = &As[g * 8 * BKB];
        lB[j] = &Bs[g * 8 * BKB];
    }

    // Fragment addresses: A[m=lane&15][k=(lane>>4)*32 + 0..31]; 32B = two b128
    // at logical chunks {2q, 2q+1}, physical chunk = logical ^ (row&7).
    const int ln = lane & 15;
    const int q  = lane >> 4;
    int offA_lo[4], offA_hi[4], offB_lo[4], offB_hi[4];
    #pragma unroll
    for (int f = 0; f < 4; ++f) {
        const int ra  = wm * 64 + f * 16 + ln;
        const int rb  = wn * 64 + f * 16 + ln;
        const int plo = (((q << 1)    ) ^ (ln & 7)) << 4;
        const int phi = (((q << 1) | 1) ^ (ln & 7)) << 4;
        offA_lo[f] = ra * BKB + plo;  offA_hi[f] = ra * BKB + phi;
        offB_lo[f] = rb * BKB + plo;  offB_hi[f] = rb * BKB + phi;
    }

    f32x4 acc[4][4] = {};

    for (int kt = 0; kt < KITER; ++kt) {
        __syncthreads();   // previous tile fully consumed
        #pragma unroll
        for (int j = 0; j < 4; ++j) load16_lds(gA[j], lA[j]);
        #pragma unroll
        for (int j = 0; j < 4; ++j) load16_lds(gB[j], lB[j]);
        #pragma unroll
        for (int j = 0; j < 4; ++j) { gA[j] += BKB; gB[j] += BKB; }
        __syncthreads();   // staged data visible

        union AB { v8i v; v4i h[2]; };
        v8i av[4], bv[4];
        #pragma unroll
        for (int f = 0; f < 4; ++f) {
            AB a, b;
            a.h[0] = *(const v4i*)&As[offA_lo[f]];
            a.h[1] = *(const v4i*)&As[offA_hi[f]];
            b.h[0] = *(const v4i*)&Bs[offB_lo[f]];
            b.h[1] = *(const v4i*)&Bs[offB_hi[f]];
            av[f] = a.v; bv[f] = b.v;
        }
        #pragma unroll
        for (int fm = 0; fm < 4; ++fm)
            #pragma unroll
            for (int fn = 0; fn < 4; ++fn)
                acc[fm][fn] = __builtin_amdgcn_mfma_scale_f32_16x16x128_f8f6f4(
                    av[fm], bv[fn], acc[fm][fn],
                    0, 0,            // cbsz=fp8(e4m3), blgp=fp8(e4m3)
                    0, 0x7F,         // A scale: byte0 = 127 -> 2^0
                    0, 0x7F);        // B scale: unit
    }

    // Epilogue: C/D col = lane&15, row = (lane>>4)*4 + reg (same as bf16 16x16).
    // W was pre-scaled by 16 -> compensate with WINV before exp/sel.
    const int lq = lane >> 4;
    float rs[4][4];
    #pragma unroll
    for (int fm = 0; fm < 4; ++fm) {
        #pragma unroll
        for (int reg = 0; reg < 4; ++reg) {
            const int row_l = wm * 64 + fm * 16 + lq * 4 + reg;
            const int id    = ids_s[row_l];
            float s = 0.f;
            #pragma unroll
            for (int fn = 0; fn < 4; ++fn) {
                float v = acc[fm][fn][reg] * WINV;
                int col_g = colB + wn * 64 + fn * 16 + ln;
                if (id == col_g) sel[rowA + row_l] = v;  // unique writer per token
                s += __expf(v);
            }
            rs[fm][reg] = s;
        }
    }
    #pragma unroll
    for (int m = 1; m < 16; m <<= 1) {
        #pragma unroll
        for (int fm = 0; fm < 4; ++fm)
            #pragma unroll
            for (int reg = 0; reg < 4; ++reg)
                rs[fm][reg] += __shfl_xor(rs[fm][reg], m, 64);
    }
    if (ln == 0) {
        #pragma unroll
        for (int fm = 0; fm < 4; ++fm)
            #pragma unroll
            for (int reg = 0; reg < 4; ++reg)
                sums_s[wn][wm * 64 + fm * 16 + lq * 4 + reg] = rs[fm][reg];
    }
    __syncthreads();
    if (tid < BM) {
        float tot = sums_s[0][tid] + sums_s[1][tid];
        part[(size_t)(rowA + tid) * NVT + tn] = tot;
    }
}

// One wave per token: lse = log(sum partials), GRPO per-token loss, block partials.
__global__ __launch_bounds__(256) void finalize(
    const float* __restrict__ pp, const float* __restrict__ pr,
    const float* __restrict__ sp, const float* __restrict__ sr,
    const int* __restrict__ mask, const float* __restrict__ adv,
    const float* __restrict__ oldlp,
    float* __restrict__ bsum, float* __restrict__ bmsum)
{
    const int lane = threadIdx.x & 63;
    const int wid  = threadIdx.x >> 6;
    const int t    = blockIdx.x * 4 + wid;

    float s_p = 0.f, s_r = 0.f;
    for (int i = lane; i < NVT; i += 64) {
        s_p += pp[(size_t)t * NVT + i];
        s_r += pr[(size_t)t * NVT + i];
    }
    #pragma unroll
    for (int k = 1; k < 64; k <<= 1) {
        s_p += __shfl_xor(s_p, k, 64);
        s_r += __shfl_xor(s_r, k, 64);
    }
    __shared__ float ls[4], ms[4];
    if (lane == 0) {
        float p  = sp[t] - logf(s_p);
        float r  = sr[t] - logf(s_r);
        float c1 = expf(p - oldlp[t]);
        float c2 = fminf(fmaxf(c1, 1.0f - EPS_LO_), 1.0f + EPS_HI_);
        float a  = adv[t >> 10];                 // T = 1024
        float ptl = -fminf(c1 * a, c2 * a);
        float d   = r - p;
        ptl += BETA_ * (expf(d) - d - 1.0f);
        float mm = (float)mask[t];
        ls[wid] = ptl * mm;
        ms[wid] = mm;
    }
    __syncthreads();
    if (threadIdx.x == 0) {
        bsum[blockIdx.x]  = ls[0] + ls[1] + ls[2] + ls[3];
        bmsum[blockIdx.x] = ms[0] + ms[1] + ms[2] + ms[3];
    }
}

__global__ __launch_bounds__(256) void final_reduce(
    const float* __restrict__ bs, const float* __restrict__ bm, float* __restrict__ out)
{
    const int tid = threadIdx.x;
    float s = 0.f, m = 0.f;
    for (int i = tid; i < M_TOK / 4; i += 256) { s += bs[i]; m += bm[i]; }
    #pragma unroll
    for (int k = 1; k < 64; k <<= 1) {
        s += __shfl_xor(s, k, 64);
        m += __shfl_xor(m, k, 64);
    }
    __shared__ float ss[4], sm[4];
    if ((tid & 63) == 0) { ss[tid >> 6] = s; sm[tid >> 6] = m; }
    __syncthreads();
    if (tid == 0) {
        float S = ss[0] + ss[1] + ss[2] + ss[3];
        float M = sm[0] + sm[1] + sm[2] + sm[3];
        out[0] = S / fmaxf(M, 1.0f);
    }
}

extern "C" void kernel_launch(void* const* d_in, const int* in_sizes, int n_in,
                              void* d_out, int out_size, void* d_ws, size_t ws_size,
                              hipStream_t stream) {
    const float* x     = (const float*)d_in[0];
    const float* rx    = (const float*)d_in[1];
    const float* w     = (const float*)d_in[2];
    const float* rw    = (const float*)d_in[3];
    const int*   ids   = (const int*)d_in[4];
    const int*   mask  = (const int*)d_in[5];
    const float* adv   = (const float*)d_in[6];
    const float* oldlp = (const float*)d_in[7];
    float* out = (float*)d_out;

    char* ws = (char*)d_ws;
    size_t off = 0;
    auto alloc = [&](size_t bytes) -> void* {
        void* p = ws + off;
        off += (bytes + 255) & ~(size_t)255;
        return p;
    };
    uint8_t* xb  = (uint8_t*)alloc((size_t)M_TOK * H_);
    uint8_t* rxb = (uint8_t*)alloc((size_t)M_TOK * H_);
    uint8_t* wb  = (uint8_t*)alloc((size_t)V_ * H_);
    uint8_t* rwb = (uint8_t*)alloc((size_t)V_ * H_);
    float* pp    = (float*)alloc((size_t)M_TOK * NVT * 4);
    float* pr    = (float*)alloc((size_t)M_TOK * NVT * 4);
    float* sp    = (float*)alloc((size_t)M_TOK * 4);
    float* sr    = (float*)alloc((size_t)M_TOK * 4);
    float* bsum  = (float*)alloc((M_TOK / 4) * 4);
    float* bmsum = (float*)alloc((M_TOK / 4) * 4);

    const int n8x = M_TOK * H_ / 8;   // 1,048,576
    const int n8w = V_ * H_ / 8;      // 8,192,000
    cvt_fp8<<<(n8x + 255) / 256, 256, 0, stream>>>((const float4*)x,  (uint2*)xb,  n8x, 1.0f);
    cvt_fp8<<<(n8x + 255) / 256, 256, 0, stream>>>((const float4*)rx, (uint2*)rxb, n8x, 1.0f);
    cvt_fp8<<<(n8w + 255) / 256, 256, 0, stream>>>((const float4*)w,  (uint2*)wb,  n8w, WSCALE);
    cvt_fp8<<<(n8w + 255) / 256, 256, 0, stream>>>((const float4*)rw, (uint2*)rwb, n8w, WSCALE);

    dim3 grid(M_TOK / BM, V_ / BN, 2);   // token-tile fastest -> W-tile L2/L3 reuse
    gemm_lse<<<grid, 256, 0, stream>>>(xb, wb, rxb, rwb, ids, pp, pr, sp, sr);

    finalize<<<M_TOK / 4, 256, 0, stream>>>(pp, pr, sp, sr, mask, adv, oldlp, bsum, bmsum);
    final_reduce<<<1, 256, 0, stream>>>(bsum, bmsum, out);
}